// Round 18
// baseline (93.528 us; speedup 1.0000x reference)
//
#include <hip/hip_runtime.h>
#include <hip/hip_bf16.h>

#define N_Q    20
#define DIM    (1 << N_Q)      // 1048576
#define BATCH  4
#define NGATES 19
#define L2OFF  117             // 6n-3 : second xyz layer offset
#define GSTRIDE 32             // per-gate: 16 g + 16 gs(swapped-negated)

typedef float2 c32;
typedef __attribute__((ext_vector_type(2))) float fv2;
typedef __attribute__((ext_vector_type(8))) short short8;
typedef __attribute__((ext_vector_type(4))) float f32x4;
typedef __attribute__((ext_vector_type(4))) unsigned int u32x4;

__device__ __forceinline__ c32 cmul(c32 a, c32 b) {
    return make_float2(fmaf(a.x, b.x, -a.y * b.y), fmaf(a.x, b.y, a.y * b.x));
}
__device__ __forceinline__ c32 cmadd(c32 acc, c32 a, c32 b) {
    acc.x = fmaf(a.x, b.x, fmaf(-a.y, b.y, acc.x));
    acc.y = fmaf(a.x, b.y, fmaf(a.y, b.x, acc.y));
    return acc;
}
__device__ __forceinline__ unsigned short f2bf(float f) {
    union { float f; unsigned u; } v; v.f = f;
    unsigned r = v.u + 0x7FFFu + ((v.u >> 16) & 1u);
    return (unsigned short)(r >> 16);
}
__device__ __forceinline__ unsigned pack_bf2(float re, float im) {
    return (unsigned)f2bf(re) | ((unsigned)f2bf(im) << 16);
}
__device__ __forceinline__ fv2 unpack_bf2(unsigned w) {
    union { unsigned u; float f; } lo, hi;
    lo.u = (w & 0xFFFFu) << 16;
    hi.u = w & 0xFFFF0000u;
    return (fv2){lo.f, hi.f};
}
__device__ __forceinline__ void gll16(const void* g, void* l) {
    __builtin_amdgcn_global_load_lds((const __attribute__((address_space(1))) void*)g,
                                     (__attribute__((address_space(3))) void*)l, 16, 0, 0);
}

__device__ void mm2(const c32 A[2][2], const c32 B[2][2], c32 C[2][2]) {
    for (int i = 0; i < 2; i++)
        for (int j = 0; j < 2; j++) {
            c32 s = make_float2(0.f, 0.f);
            for (int k = 0; k < 2; k++) s = cmadd(s, A[i][k], B[k][j]);
            C[i][j] = s;
        }
}
__device__ void mm4(const c32 A[4][4], const c32 B[4][4], c32 C[4][4]) {
    for (int i = 0; i < 4; i++)
        for (int j = 0; j < 4; j++) {
            c32 s = make_float2(0.f, 0.f);
            for (int k = 0; k < 4; k++) s = cmadd(s, A[i][k], B[k][j]);
            C[i][j] = s;
        }
}
__device__ void single_u(const float* w, int base, c32 U[2][2]) {
    const float WM = 0.63245553203367586640f;  // sqrt(2/5)
    float hx = w[base] * WM * 0.5f, hy = w[base + 1] * WM * 0.5f, hz = w[base + 2] * WM * 0.5f;
    float cx = cosf(hx), sx = sinf(hx);
    float cy = cosf(hy), sy = sinf(hy);
    float cz = cosf(hz), sz = sinf(hz);
    c32 RX[2][2] = {{{cx, 0.f}, {0.f, -sx}}, {{0.f, -sx}, {cx, 0.f}}};
    c32 RY[2][2] = {{{cy, 0.f}, {-sy, 0.f}}, {{sy, 0.f}, {cy, 0.f}}};
    c32 RZ[2][2] = {{{cz, -sz}, {0.f, 0.f}}, {{0.f, 0.f}, {cz, sz}}};
    c32 T[2][2];
    mm2(RY, RX, T);
    mm2(RZ, T, U);
}
__device__ void kron22(const c32 A[2][2], const c32 B[2][2], c32 K[4][4]) {
    for (int i = 0; i < 2; i++)
        for (int j = 0; j < 2; j++)
            for (int k = 0; k < 2; k++)
                for (int l = 0; l < 2; l++)
                    K[i * 2 + j][k * 2 + l] = cmul(A[i][k], B[j][l]);
}

// Build the 19 fused 4x4 staircase gates; emit both g and gs=(-g.y, g.x) tables.
__global__ void build_gates(const float* __restrict__ w, c32* __restrict__ G) {
    int q = threadIdx.x;
    if (q >= NGATES) return;
    const float WM = 0.63245553203367586640f;
    float hx = w[60 + 3 * q] * WM * 0.5f;
    float hy = w[61 + 3 * q] * WM * 0.5f;
    float hz = w[62 + 3 * q] * WM * 0.5f;
    float cx = cosf(hx), sx = sinf(hx);
    float cy = cosf(hy), sy = sinf(hy);
    float cz = cosf(hz), sz = sinf(hz);
    c32 RXX[4][4], RYY[4][4], RZZ[4][4];
    for (int i = 0; i < 4; i++)
        for (int j = 0; j < 4; j++) {
            RXX[i][j] = make_float2(0.f, 0.f);
            RYY[i][j] = make_float2(0.f, 0.f);
            RZZ[i][j] = make_float2(0.f, 0.f);
        }
    for (int i = 0; i < 4; i++) {
        RXX[i][i]     = make_float2(cx, 0.f);
        RXX[i][3 - i] = make_float2(0.f, -sx);
        RYY[i][i]     = make_float2(cy, 0.f);
    }
    RYY[0][3] = make_float2(0.f,  sy);
    RYY[1][2] = make_float2(0.f, -sy);
    RYY[2][1] = make_float2(0.f, -sy);
    RYY[3][0] = make_float2(0.f,  sy);
    RZZ[0][0] = make_float2(cz, -sz);
    RZZ[1][1] = make_float2(cz,  sz);
    RZZ[2][2] = make_float2(cz,  sz);
    RZZ[3][3] = make_float2(cz, -sz);
    c32 T[4][4], M[4][4];
    mm4(RYY, RXX, T);
    mm4(RZZ, T, M);

    c32 I2m[2][2] = {{{1.f, 0.f}, {0.f, 0.f}}, {{0.f, 0.f}, {1.f, 0.f}}};
    c32 Ua[2][2], Ub[2][2], Pre[4][4], Post[4][4];
    if (q == 0) {
        single_u(w, 0, Ua);
        single_u(w, 3, Ub);
        kron22(Ua, Ub, Pre);
    } else {
        single_u(w, 3 * (q + 1), Ub);
        kron22(I2m, Ub, Pre);
    }
    if (q == NGATES - 1) {
        single_u(w, L2OFF + 3 * 18, Ua);
        single_u(w, L2OFF + 3 * 19, Ub);
        kron22(Ua, Ub, Post);
    } else {
        single_u(w, L2OFF + 3 * q, Ua);
        kron22(Ua, I2m, Post);
    }
    c32 T2[4][4], Gq[4][4];
    mm4(M, Pre, T2);
    mm4(Post, T2, Gq);
    for (int i = 0; i < 4; i++)
        for (int j = 0; j < 4; j++) {
            c32 g = Gq[i][j];
            G[q * GSTRIDE + i * 4 + j]      = g;
            G[q * GSTRIDE + 16 + i * 4 + j] = make_float2(-g.y, g.x);
        }
}

// Packed complex 4x4 apply: x.xx*g + x.yy*gs -> 2 v_pk_fma per complex MAC.
__device__ __forceinline__ void apply4pk(const fv2 g[16], const fv2 gs[16],
                                         fv2& x0, fv2& x1, fv2& x2, fv2& x3) {
    fv2 a0 = (fv2)(x0[0]), b0 = (fv2)(x0[1]);
    fv2 a1 = (fv2)(x1[0]), b1 = (fv2)(x1[1]);
    fv2 a2 = (fv2)(x2[0]), b2 = (fv2)(x2[1]);
    fv2 a3 = (fv2)(x3[0]), b3 = (fv2)(x3[1]);
    fv2 r0 = a0 * g[0];  r0 += b0 * gs[0];  r0 += a1 * g[1];  r0 += b1 * gs[1];
    r0 += a2 * g[2];     r0 += b2 * gs[2];  r0 += a3 * g[3];  r0 += b3 * gs[3];
    fv2 r1 = a0 * g[4];  r1 += b0 * gs[4];  r1 += a1 * g[5];  r1 += b1 * gs[5];
    r1 += a2 * g[6];     r1 += b2 * gs[6];  r1 += a3 * g[7];  r1 += b3 * gs[7];
    fv2 r2 = a0 * g[8];  r2 += b0 * gs[8];  r2 += a1 * g[9];  r2 += b1 * gs[9];
    r2 += a2 * g[10];    r2 += b2 * gs[10]; r2 += a3 * g[11]; r2 += b3 * gs[11];
    fv2 r3 = a0 * g[12]; r3 += b0 * gs[12]; r3 += a1 * g[13]; r3 += b1 * gs[13];
    r3 += a2 * g[14];    r3 += b2 * gs[14]; r3 += a3 * g[15]; r3 += b3 * gs[15];
    x0 = r0; x1 = r1; x2 = r2; x3 = r3;
}
__device__ __forceinline__ void load_gate2(const fv2* __restrict__ gp, fv2 g[16], fv2 gs[16]) {
#pragma unroll
    for (int k = 0; k < 16; k++) { g[k] = gp[k]; gs[k] = gp[16 + k]; }
}
template <int LO>
__device__ __forceinline__ void gate_on32(fv2 v[32], const fv2 g[16], const fv2 gs[16]) {
#pragma unroll
    for (int m = 0; m < 8; ++m) {
        const int j0 = ((m >> LO) << (LO + 2)) | (m & ((1 << LO) - 1));
        const int s = 1 << LO;
        apply4pk(g, gs, v[j0], v[j0 + s], v[j0 + 2 * s], v[j0 + 3 * s]);
    }
}
template <int LO>
__device__ __forceinline__ void gate_on16(fv2* v, const fv2 g[16], const fv2 gs[16]) {
#pragma unroll
    for (int m = 0; m < 4; ++m) {
        const int j0 = ((m >> LO) << (LO + 2)) | (m & ((1 << LO) - 1));
        const int s = 1 << LO;
        apply4pk(g, gs, v[j0], v[j0 + s], v[j0 + 2 * s], v[j0 + 3 * s]);
    }
}

// u32 packed-bf16 LDS exchange swizzle for pass_b2 (bank = addr&31):
// XOR bits [9:5] into [4:0] -> all store/load patterns <=2-way (analyzed).
#define PIDX(l) ((l) ^ ((((l) >> 5)) & 31))
// Transposed-epilogue exchange (u32 space): write ~8-way (cheap), read ~2-way.
#define TIDX8(a, tl) (((a) << 3) | ((((tl) ^ ((a) >> 2) ^ ((a) >> 5))) & 7))

// Pass A2: gates 0..6. LDS exchange now PACKED bf16 u32 (32 KB total) ->
// 4 blocks/CU (was 2). Output psi packed bf16.
__global__ __launch_bounds__(256, 4) void pass_a2(const float* __restrict__ x,
                                                  unsigned* __restrict__ psiB,
                                                  const c32* __restrict__ Gall) {
    __shared__ __align__(16) char smem[32768];
    float* xs = (float*)smem;        // [256][32] f32, 16B-slot swizzled (32 KB)
    unsigned* su = (unsigned*)smem;  // 8192 u32 packed exchange view (32 KB)
    const fv2* Gf = (const fv2*)Gall;
    int b = blockIdx.x >> 7;
    int c0 = (blockIdx.x & 127) << 5;
    const float* xp = x + ((size_t)b << 20) + c0;
    unsigned* ppb = psiB + ((size_t)b << 20) + c0;
    int t = threadIdx.x;
#pragma unroll
    for (int i = 0; i < 8; ++i) {
        int f4 = t + (i << 8);
        int row = f4 >> 3, sl = f4 & 7;
        float4 v = *reinterpret_cast<const float4*>(xp + (size_t)row * 4096 + sl * 4);
        reinterpret_cast<float4*>(xs)[row * 8 + (sl ^ (row & 7))] = v;
    }
    __syncthreads();
    int col = t & 31, rlow = t >> 5;
    fv2 v[32], g[16], gs[16];
#pragma unroll
    for (int j = 0; j < 32; ++j) {
        int row = (j << 3) | rlow;
        float re = xs[row * 32 + ((((col >> 2) ^ (row & 7)) << 2) | (col & 3))];
        v[j] = (fv2){re, 0.f};
    }
    __syncthreads();
    load_gate2(Gf + 0 * GSTRIDE, g, gs);  gate_on32<3>(v, g, gs);
    load_gate2(Gf + 1 * GSTRIDE, g, gs);  gate_on32<2>(v, g, gs);
    load_gate2(Gf + 2 * GSTRIDE, g, gs);  gate_on32<1>(v, g, gs);
    load_gate2(Gf + 3 * GSTRIDE, g, gs);  gate_on32<0>(v, g, gs);
    // packed exchange: store consecutive (free), read 2-way (free) -- no swizzle
#pragma unroll
    for (int j = 0; j < 32; ++j) {
        int l = ((((j << 3) | rlow) << 5)) | col;
        su[l] = pack_bf2(v[j][0], v[j][1]);
    }
    __syncthreads();
    int rhi = t >> 5;
#pragma unroll
    for (int rtop = 0; rtop < 2; ++rtop)
#pragma unroll
        for (int j = 0; j < 16; ++j) {
            int row = (rtop << 7) | (rhi << 4) | j;
            int l = (row << 5) | col;
            v[rtop * 16 + j] = unpack_bf2(su[l]);
        }
    load_gate2(Gf + 4 * GSTRIDE, g, gs);  gate_on16<2>(v, g, gs);  gate_on16<2>(v + 16, g, gs);
    load_gate2(Gf + 5 * GSTRIDE, g, gs);  gate_on16<1>(v, g, gs);  gate_on16<1>(v + 16, g, gs);
    load_gate2(Gf + 6 * GSTRIDE, g, gs);  gate_on16<0>(v, g, gs);  gate_on16<0>(v + 16, g, gs);
#pragma unroll
    for (int rtop = 0; rtop < 2; ++rtop)
#pragma unroll
        for (int j = 0; j < 16; ++j) {
            int row = (rtop << 7) | (rhi << 4) | j;
            fv2 val = v[rtop * 16 + j];
            ppb[(size_t)row * 4096 + col] = pack_bf2(val[0], val[1]);
        }
}

// Pass B2: gates 7..18. LDS exchanges PACKED bf16 u32 (32 KB) -> 4 blocks/CU.
// Fused transpose epilogue ([a][t] output, TIDX8, pack-before-LDS).
__global__ __launch_bounds__(256, 4) void pass_b2(const unsigned* __restrict__ psiB,
                                                  unsigned short* __restrict__ Art,
                                                  unsigned short* __restrict__ Ait,
                                                  const c32* __restrict__ Gall) {
    __shared__ unsigned su[8192];    // 32 KB
    const fv2* Gf = (const fv2*)Gall;
    int b = blockIdx.x >> 7;
    int chunk = blockIdx.x & 127;
    const unsigned* ppb = psiB + ((size_t)b << 20) + ((size_t)chunk << 13);
    int t = threadIdx.x;
    fv2 v[32], g[16], gs[16];
#pragma unroll
    for (int j = 0; j < 32; ++j) v[j] = unpack_bf2(ppb[(j << 8) | t]);
    load_gate2(Gf + 7 * GSTRIDE, g, gs);   gate_on32<3>(v, g, gs);
    load_gate2(Gf + 8 * GSTRIDE, g, gs);   gate_on32<2>(v, g, gs);
    load_gate2(Gf + 9 * GSTRIDE, g, gs);   gate_on32<1>(v, g, gs);
    load_gate2(Gf + 10 * GSTRIDE, g, gs);  gate_on32<0>(v, g, gs);
#pragma unroll
    for (int j = 0; j < 32; ++j) { int l = (j << 8) | t; su[PIDX(l)] = pack_bf2(v[j][0], v[j][1]); }
    __syncthreads();
    int hi2 = (t >> 4) << 9, lo2 = t & 15;
#pragma unroll
    for (int j = 0; j < 32; ++j) { int l = hi2 | (j << 4) | lo2; v[j] = unpack_bf2(su[PIDX(l)]); }
    load_gate2(Gf + 11 * GSTRIDE, g, gs);  gate_on32<3>(v, g, gs);
    load_gate2(Gf + 12 * GSTRIDE, g, gs);  gate_on32<2>(v, g, gs);
    load_gate2(Gf + 13 * GSTRIDE, g, gs);  gate_on32<1>(v, g, gs);
    load_gate2(Gf + 14 * GSTRIDE, g, gs);  gate_on32<0>(v, g, gs);
    __syncthreads();
#pragma unroll
    for (int j = 0; j < 32; ++j) { int l = hi2 | (j << 4) | lo2; su[PIDX(l)] = pack_bf2(v[j][0], v[j][1]); }
    __syncthreads();
#pragma unroll
    for (int j = 0; j < 32; ++j) { int l = (t << 5) | j; v[j] = unpack_bf2(su[PIDX(l)]); }
    load_gate2(Gf + 15 * GSTRIDE, g, gs);  gate_on32<3>(v, g, gs);
    load_gate2(Gf + 16 * GSTRIDE, g, gs);  gate_on32<2>(v, g, gs);
    load_gate2(Gf + 17 * GSTRIDE, g, gs);  gate_on32<1>(v, g, gs);
    load_gate2(Gf + 18 * GSTRIDE, g, gs);  gate_on32<0>(v, g, gs);
    // ---- transpose epilogue: pack before LDS (output bit-identical to r17) ----
    __syncthreads();
    {
        int tlw = t >> 5;
        int abase = (t & 31) << 5;
#pragma unroll
        for (int j = 0; j < 32; ++j) {
            int a = abase + j;
            su[TIDX8(a, tlw)] = pack_bf2(v[j][0], v[j][1]);
        }
    }
    __syncthreads();
    {
        int w = t >> 6, lane = t & 63;
        size_t gb = (size_t)b << 20;
#pragma unroll
        for (int i = 0; i < 4; ++i) {
            int a = (w << 8) | (i << 6) | lane;
            unsigned short rr[8], ri[8];
#pragma unroll
            for (int tl = 0; tl < 8; ++tl) {
                unsigned q = su[TIDX8(a, tl)];
                rr[tl] = (unsigned short)(q & 0xFFFFu);
                ri[tl] = (unsigned short)(q >> 16);
            }
            size_t dst = gb + ((size_t)a << 10) + (chunk << 3);   // [a][t] layout
            *reinterpret_cast<float4*>(Art + dst) = *reinterpret_cast<float4*>(rr);
            *reinterpret_cast<float4*>(Ait + dst) = *reinterpret_cast<float4*>(ri);
        }
    }
}

// gram_mfma5c: r14/r17 best variant, byte-identical.
__global__ __launch_bounds__(512) void gram_mfma5c(const unsigned short* __restrict__ Art,
                                                   const unsigned short* __restrict__ Ait,
                                                   float2* __restrict__ out) {
    __shared__ __align__(16) unsigned short lds[2][4][8192];   // 128 KB
    int hw = blockIdx.x;
    int virt = (hw & 7) * 18 + (hw >> 3);        // bijective: 144 = 8*18, XCD-chunked
    int b = virt / 36;
    int rem = virt - b * 36;                     // triangular decode over 8x8, ia <= ic
    int ia = 0;
    while (rem >= 8 - ia) { rem -= 8 - ia; ++ia; }
    int ic = ia + rem;
    int a0 = ia * 128, c0 = ic * 128;
    int tid = threadIdx.x;
    int lane = tid & 63, w = tid >> 6;           // 8 waves
    int wm = w & 3, wn = w >> 2;                 // wave-tile: rows wm*32, cols wn*64
    int arr = w >> 1, half = w & 1;
    const unsigned short* sp = (arr & 1) ? Ait : Art;
    int prow = (arr < 2) ? a0 : c0;
    int srow = lane >> 3, sslot = lane & 7;
    size_t gb = (size_t)b << 20;

    f32x4 accRe[2][4], accIm[2][4];
#pragma unroll
    for (int m = 0; m < 2; m++)
#pragma unroll
        for (int n = 0; n < 4; n++) { accRe[m][n] = (f32x4)0.f; accIm[m][n] = (f32x4)0.f; }

#define STAGE5(KT, BUF)                                                                   \
    {                                                                                     \
        _Pragma("unroll")                                                                 \
        for (int i = 0; i < 8; ++i) {                                                     \
            int r = (half << 6) | (i << 3) | srow;                                        \
            int sl = sslot ^ srow;                                                        \
            const unsigned short* gp = sp + gb + ((size_t)(prow + r) << 10) + (KT) * 64 + sl * 8; \
            gll16(gp, &lds[BUF][arr][((half << 6) | (i << 3)) * 64 + lane * 8]);          \
        }                                                                                 \
    }

    STAGE5(0, 0);
    for (int kt = 0; kt < 16; ++kt) {
        int cur = kt & 1;
        asm volatile("s_waitcnt vmcnt(0)" ::: "memory");
        __builtin_amdgcn_s_barrier();
        __builtin_amdgcn_sched_barrier(0);
        if (kt < 15) STAGE5(kt + 1, cur ^ 1);
        __builtin_amdgcn_s_setprio(1);
#pragma unroll
        for (int kk = 0; kk < 2; ++kk) {
            int sbase = kk * 4 + (lane >> 4);    // 16B-slot index 0..7
            short8 am[2][2], bn[4][2];
#pragma unroll
            for (int m = 0; m < 2; m++) {
                int r = wm * 32 + m * 16 + (lane & 15);
                int off = r * 64 + ((sbase ^ (r & 7)) << 3);
                am[m][0] = *reinterpret_cast<const short8*>(&lds[cur][0][off]);
                am[m][1] = *reinterpret_cast<const short8*>(&lds[cur][1][off]);
            }
#pragma unroll
            for (int n = 0; n < 4; n++) {
                int r = wn * 64 + n * 16 + (lane & 15);
                int off = r * 64 + ((sbase ^ (r & 7)) << 3);
                bn[n][0] = *reinterpret_cast<const short8*>(&lds[cur][2][off]);
                bn[n][1] = *reinterpret_cast<const short8*>(&lds[cur][3][off]);
            }
#pragma unroll
            for (int m = 0; m < 2; m++) {
                u32x4 tn = *reinterpret_cast<u32x4*>(&am[m][0]) ^ 0x80008000u;
                short8 arn = *reinterpret_cast<short8*>(&tn);
#pragma unroll
                for (int n = 0; n < 4; n++) {
                    accRe[m][n] = __builtin_amdgcn_mfma_f32_16x16x32_bf16(am[m][0], bn[n][0], accRe[m][n], 0, 0, 0);
                    accRe[m][n] = __builtin_amdgcn_mfma_f32_16x16x32_bf16(am[m][1], bn[n][1], accRe[m][n], 0, 0, 0);
                    accIm[m][n] = __builtin_amdgcn_mfma_f32_16x16x32_bf16(am[m][1], bn[n][0], accIm[m][n], 0, 0, 0);
                    accIm[m][n] = __builtin_amdgcn_mfma_f32_16x16x32_bf16(arn,      bn[n][1], accIm[m][n], 0, 0, 0);
                }
            }
        }
        __builtin_amdgcn_s_setprio(0);
        asm volatile("s_waitcnt lgkmcnt(0)" ::: "memory");
        __builtin_amdgcn_sched_barrier(0);
    }
#undef STAGE5
    // ---- epilogue ----
    size_t ob = gb;
#pragma unroll
    for (int m = 0; m < 2; m++)
#pragma unroll
        for (int n = 0; n < 4; n++)
#pragma unroll
            for (int r = 0; r < 4; r++) {
                int a = a0 + wm * 32 + m * 16 + (lane >> 4) * 4 + r;
                int c = c0 + wn * 64 + n * 16 + (lane & 15);
                out[ob + ((size_t)a << 10) + c] = make_float2(accRe[m][n][r], accIm[m][n][r]);
            }
    if (ia != ic) {
        float2* mlds = reinterpret_cast<float2*>(&lds[0][0][0]);
#pragma unroll
        for (int h = 0; h < 2; ++h) {
            __syncthreads();
            if (wn == h) {
#pragma unroll
                for (int m = 0; m < 2; m++)
#pragma unroll
                    for (int n = 0; n < 4; n++)
#pragma unroll
                        for (int r = 0; r < 4; r++) {
                            int a_l = wm * 32 + m * 16 + (lane >> 4) * 4 + r;   // 0..127
                            int c_l = n * 16 + (lane & 15);                     // 0..63 within half
                            mlds[c_l * 131 + a_l] = make_float2(accRe[m][n][r], -accIm[m][n][r]);
                        }
            }
            __syncthreads();
#pragma unroll
            for (int i = 0; i < 16; ++i) {
                int p = tid + (i << 9);          // 8192 float2 = [64 c-rows][128 a-cols]
                int row = p >> 7, col = p & 127;
                out[ob + ((size_t)(c0 + h * 64 + row) << 10) + a0 + col] = mlds[row * 131 + col];
            }
        }
    }
}

extern "C" void kernel_launch(void* const* d_in, const int* in_sizes, int n_in,
                              void* d_out, int out_size, void* d_ws, size_t ws_size,
                              hipStream_t stream) {
    const float* x = (const float*)d_in[0];
    const float* weight = (const float*)d_in[1];
    const size_t psiBytes = (size_t)BATCH * DIM * sizeof(unsigned);  // 16 MB (packed bf16)
    unsigned* psiB = (unsigned*)d_ws;
    c32* G = (c32*)((char*)d_ws + psiBytes);                         // 19*32 c32
    unsigned short* Art = (unsigned short*)((char*)d_ws + psiBytes + 65536);
    unsigned short* Ait = Art + (size_t)BATCH * DIM;                 // 8 MB each

    build_gates<<<1, 64, 0, stream>>>(weight, G);
    pass_a2<<<BATCH * 128, 256, 0, stream>>>(x, psiB, G);            // gates 0..6 -> packed bf16 psi
    pass_b2<<<BATCH * 128, 256, 0, stream>>>(psiB, Art, Ait, G);     // gates 7..18 -> bf16 [a][t]
    gram_mfma5c<<<144, 512, 0, stream>>>(Art, Ait, (float2*)d_out);
}

// Round 19
// 92.682 us; speedup vs baseline: 1.0091x; 1.0091x over previous
//
#include <hip/hip_runtime.h>
#include <hip/hip_bf16.h>

#define N_Q    20
#define DIM    (1 << N_Q)      // 1048576
#define BATCH  4
#define NGATES 19
#define L2OFF  117             // 6n-3 : second xyz layer offset
#define GSTRIDE 32             // per-gate: 16 g + 16 gs(swapped-negated)

typedef float2 c32;
typedef __attribute__((ext_vector_type(2))) float fv2;
typedef __attribute__((ext_vector_type(8))) short short8;
typedef __attribute__((ext_vector_type(4))) float f32x4;
typedef __attribute__((ext_vector_type(4))) unsigned int u32x4;

__device__ __forceinline__ c32 cmul(c32 a, c32 b) {
    return make_float2(fmaf(a.x, b.x, -a.y * b.y), fmaf(a.x, b.y, a.y * b.x));
}
__device__ __forceinline__ c32 cmadd(c32 acc, c32 a, c32 b) {
    acc.x = fmaf(a.x, b.x, fmaf(-a.y, b.y, acc.x));
    acc.y = fmaf(a.x, b.y, fmaf(a.y, b.x, acc.y));
    return acc;
}
__device__ __forceinline__ unsigned short f2bf(float f) {
    union { float f; unsigned u; } v; v.f = f;
    unsigned r = v.u + 0x7FFFu + ((v.u >> 16) & 1u);
    return (unsigned short)(r >> 16);
}
__device__ __forceinline__ unsigned pack_bf2(float re, float im) {
    return (unsigned)f2bf(re) | ((unsigned)f2bf(im) << 16);
}
__device__ __forceinline__ fv2 unpack_bf2(unsigned w) {
    union { unsigned u; float f; } lo, hi;
    lo.u = (w & 0xFFFFu) << 16;
    hi.u = w & 0xFFFF0000u;
    return (fv2){lo.f, hi.f};
}
__device__ __forceinline__ void gll16(const void* g, void* l) {
    __builtin_amdgcn_global_load_lds((const __attribute__((address_space(1))) void*)g,
                                     (__attribute__((address_space(3))) void*)l, 16, 0, 0);
}

__device__ void mm2(const c32 A[2][2], const c32 B[2][2], c32 C[2][2]) {
    for (int i = 0; i < 2; i++)
        for (int j = 0; j < 2; j++) {
            c32 s = make_float2(0.f, 0.f);
            for (int k = 0; k < 2; k++) s = cmadd(s, A[i][k], B[k][j]);
            C[i][j] = s;
        }
}
__device__ void mm4(const c32 A[4][4], const c32 B[4][4], c32 C[4][4]) {
    for (int i = 0; i < 4; i++)
        for (int j = 0; j < 4; j++) {
            c32 s = make_float2(0.f, 0.f);
            for (int k = 0; k < 4; k++) s = cmadd(s, A[i][k], B[k][j]);
            C[i][j] = s;
        }
}
__device__ void single_u(const float* w, int base, c32 U[2][2]) {
    const float WM = 0.63245553203367586640f;  // sqrt(2/5)
    float hx = w[base] * WM * 0.5f, hy = w[base + 1] * WM * 0.5f, hz = w[base + 2] * WM * 0.5f;
    float cx = cosf(hx), sx = sinf(hx);
    float cy = cosf(hy), sy = sinf(hy);
    float cz = cosf(hz), sz = sinf(hz);
    c32 RX[2][2] = {{{cx, 0.f}, {0.f, -sx}}, {{0.f, -sx}, {cx, 0.f}}};
    c32 RY[2][2] = {{{cy, 0.f}, {-sy, 0.f}}, {{sy, 0.f}, {cy, 0.f}}};
    c32 RZ[2][2] = {{{cz, -sz}, {0.f, 0.f}}, {{0.f, 0.f}, {cz, sz}}};
    c32 T[2][2];
    mm2(RY, RX, T);
    mm2(RZ, T, U);
}
__device__ void kron22(const c32 A[2][2], const c32 B[2][2], c32 K[4][4]) {
    for (int i = 0; i < 2; i++)
        for (int j = 0; j < 2; j++)
            for (int k = 0; k < 2; k++)
                for (int l = 0; l < 2; l++)
                    K[i * 2 + j][k * 2 + l] = cmul(A[i][k], B[j][l]);
}

// Build the 19 fused 4x4 staircase gates; emit both g and gs=(-g.y, g.x) tables.
__global__ void build_gates(const float* __restrict__ w, c32* __restrict__ G) {
    int q = threadIdx.x;
    if (q >= NGATES) return;
    const float WM = 0.63245553203367586640f;
    float hx = w[60 + 3 * q] * WM * 0.5f;
    float hy = w[61 + 3 * q] * WM * 0.5f;
    float hz = w[62 + 3 * q] * WM * 0.5f;
    float cx = cosf(hx), sx = sinf(hx);
    float cy = cosf(hy), sy = sinf(hy);
    float cz = cosf(hz), sz = sinf(hz);
    c32 RXX[4][4], RYY[4][4], RZZ[4][4];
    for (int i = 0; i < 4; i++)
        for (int j = 0; j < 4; j++) {
            RXX[i][j] = make_float2(0.f, 0.f);
            RYY[i][j] = make_float2(0.f, 0.f);
            RZZ[i][j] = make_float2(0.f, 0.f);
        }
    for (int i = 0; i < 4; i++) {
        RXX[i][i]     = make_float2(cx, 0.f);
        RXX[i][3 - i] = make_float2(0.f, -sx);
        RYY[i][i]     = make_float2(cy, 0.f);
    }
    RYY[0][3] = make_float2(0.f,  sy);
    RYY[1][2] = make_float2(0.f, -sy);
    RYY[2][1] = make_float2(0.f, -sy);
    RYY[3][0] = make_float2(0.f,  sy);
    RZZ[0][0] = make_float2(cz, -sz);
    RZZ[1][1] = make_float2(cz,  sz);
    RZZ[2][2] = make_float2(cz,  sz);
    RZZ[3][3] = make_float2(cz, -sz);
    c32 T[4][4], M[4][4];
    mm4(RYY, RXX, T);
    mm4(RZZ, T, M);

    c32 I2m[2][2] = {{{1.f, 0.f}, {0.f, 0.f}}, {{0.f, 0.f}, {1.f, 0.f}}};
    c32 Ua[2][2], Ub[2][2], Pre[4][4], Post[4][4];
    if (q == 0) {
        single_u(w, 0, Ua);
        single_u(w, 3, Ub);
        kron22(Ua, Ub, Pre);
    } else {
        single_u(w, 3 * (q + 1), Ub);
        kron22(I2m, Ub, Pre);
    }
    if (q == NGATES - 1) {
        single_u(w, L2OFF + 3 * 18, Ua);
        single_u(w, L2OFF + 3 * 19, Ub);
        kron22(Ua, Ub, Post);
    } else {
        single_u(w, L2OFF + 3 * q, Ua);
        kron22(Ua, I2m, Post);
    }
    c32 T2[4][4], Gq[4][4];
    mm4(M, Pre, T2);
    mm4(Post, T2, Gq);
    for (int i = 0; i < 4; i++)
        for (int j = 0; j < 4; j++) {
            c32 g = Gq[i][j];
            G[q * GSTRIDE + i * 4 + j]      = g;
            G[q * GSTRIDE + 16 + i * 4 + j] = make_float2(-g.y, g.x);
        }
}

// Packed complex 4x4 apply: x.xx*g + x.yy*gs -> 2 v_pk_fma per complex MAC.
__device__ __forceinline__ void apply4pk(const fv2 g[16], const fv2 gs[16],
                                         fv2& x0, fv2& x1, fv2& x2, fv2& x3) {
    fv2 a0 = (fv2)(x0[0]), b0 = (fv2)(x0[1]);
    fv2 a1 = (fv2)(x1[0]), b1 = (fv2)(x1[1]);
    fv2 a2 = (fv2)(x2[0]), b2 = (fv2)(x2[1]);
    fv2 a3 = (fv2)(x3[0]), b3 = (fv2)(x3[1]);
    fv2 r0 = a0 * g[0];  r0 += b0 * gs[0];  r0 += a1 * g[1];  r0 += b1 * gs[1];
    r0 += a2 * g[2];     r0 += b2 * gs[2];  r0 += a3 * g[3];  r0 += b3 * gs[3];
    fv2 r1 = a0 * g[4];  r1 += b0 * gs[4];  r1 += a1 * g[5];  r1 += b1 * gs[5];
    r1 += a2 * g[6];     r1 += b2 * gs[6];  r1 += a3 * g[7];  r1 += b3 * gs[7];
    fv2 r2 = a0 * g[8];  r2 += b0 * gs[8];  r2 += a1 * g[9];  r2 += b1 * gs[9];
    r2 += a2 * g[10];    r2 += b2 * gs[10]; r2 += a3 * g[11]; r2 += b3 * gs[11];
    fv2 r3 = a0 * g[12]; r3 += b0 * gs[12]; r3 += a1 * g[13]; r3 += b1 * gs[13];
    r3 += a2 * g[14];    r3 += b2 * gs[14]; r3 += a3 * g[15]; r3 += b3 * gs[15];
    x0 = r0; x1 = r1; x2 = r2; x3 = r3;
}
__device__ __forceinline__ void load_gate2(const fv2* __restrict__ gp, fv2 g[16], fv2 gs[16]) {
#pragma unroll
    for (int k = 0; k < 16; k++) { g[k] = gp[k]; gs[k] = gp[16 + k]; }
}
template <int LO>
__device__ __forceinline__ void gate_on32(fv2 v[32], const fv2 g[16], const fv2 gs[16]) {
#pragma unroll
    for (int m = 0; m < 8; ++m) {
        const int j0 = ((m >> LO) << (LO + 2)) | (m & ((1 << LO) - 1));
        const int s = 1 << LO;
        apply4pk(g, gs, v[j0], v[j0 + s], v[j0 + 2 * s], v[j0 + 3 * s]);
    }
}
template <int LO>
__device__ __forceinline__ void gate_on16(fv2* v, const fv2 g[16], const fv2 gs[16]) {
#pragma unroll
    for (int m = 0; m < 4; ++m) {
        const int j0 = ((m >> LO) << (LO + 2)) | (m & ((1 << LO) - 1));
        const int s = 1 << LO;
        apply4pk(g, gs, v[j0], v[j0 + s], v[j0 + 2 * s], v[j0 + 3 * s]);
    }
}

// XOR swizzle for 8192-elem LDS exchanges (verified <=4-way for all patterns used).
#define SIDX(l) ((l) ^ ((((l) >> 5) & 15)))
// Transposed-epilogue exchange, FIXED swizzle (r16): tl' mixes a's low bits so
// epilogue reads (lanes consecutive in a) spread banks (<=4-way; was 16-way).
#define TIDX8(a, tl) (((a) << 3) | ((((tl) ^ ((a) >> 2) ^ ((a) >> 5))) & 7))

// Pass A2: gates 0..6 (psi bits 19..12). Output psi PACKED bf16 (u32 re|im).
__global__ __launch_bounds__(256) void pass_a2(const float* __restrict__ x,
                                               unsigned* __restrict__ psiB,
                                               const c32* __restrict__ Gall) {
    __shared__ __align__(16) char smem[65536];
    float* xs = (float*)smem;        // [256][32] f32, 16B-slot swizzled (32 KB)
    fv2* s = (fv2*)smem;             // 8192 fv2 exchange view (64 KB)
    const fv2* Gf = (const fv2*)Gall;
    int b = blockIdx.x >> 7;
    int c0 = (blockIdx.x & 127) << 5;
    const float* xp = x + ((size_t)b << 20) + c0;
    unsigned* ppb = psiB + ((size_t)b << 20) + c0;
    int t = threadIdx.x;
#pragma unroll
    for (int i = 0; i < 8; ++i) {
        int f4 = t + (i << 8);
        int row = f4 >> 3, sl = f4 & 7;
        float4 v = *reinterpret_cast<const float4*>(xp + (size_t)row * 4096 + sl * 4);
        reinterpret_cast<float4*>(xs)[row * 8 + (sl ^ (row & 7))] = v;
    }
    __syncthreads();
    int col = t & 31, rlow = t >> 5;
    fv2 v[32], g[16], gs[16];
#pragma unroll
    for (int j = 0; j < 32; ++j) {
        int row = (j << 3) | rlow;
        float re = xs[row * 32 + ((((col >> 2) ^ (row & 7)) << 2) | (col & 3))];
        v[j] = (fv2){re, 0.f};
    }
    __syncthreads();
    load_gate2(Gf + 0 * GSTRIDE, g, gs);  gate_on32<3>(v, g, gs);
    load_gate2(Gf + 1 * GSTRIDE, g, gs);  gate_on32<2>(v, g, gs);
    load_gate2(Gf + 2 * GSTRIDE, g, gs);  gate_on32<1>(v, g, gs);
    load_gate2(Gf + 3 * GSTRIDE, g, gs);  gate_on32<0>(v, g, gs);
#pragma unroll
    for (int j = 0; j < 32; ++j) {
        int l = ((((j << 3) | rlow) << 5)) | col;
        s[SIDX(l)] = v[j];
    }
    __syncthreads();
    int rhi = t >> 5;
#pragma unroll
    for (int rtop = 0; rtop < 2; ++rtop)
#pragma unroll
        for (int j = 0; j < 16; ++j) {
            int row = (rtop << 7) | (rhi << 4) | j;
            int l = (row << 5) | col;
            v[rtop * 16 + j] = s[SIDX(l)];
        }
    load_gate2(Gf + 4 * GSTRIDE, g, gs);  gate_on16<2>(v, g, gs);  gate_on16<2>(v + 16, g, gs);
    load_gate2(Gf + 5 * GSTRIDE, g, gs);  gate_on16<1>(v, g, gs);  gate_on16<1>(v + 16, g, gs);
    load_gate2(Gf + 6 * GSTRIDE, g, gs);  gate_on16<0>(v, g, gs);  gate_on16<0>(v + 16, g, gs);
#pragma unroll
    for (int rtop = 0; rtop < 2; ++rtop)
#pragma unroll
        for (int j = 0; j < 16; ++j) {
            int row = (rtop << 7) | (rhi << 4) | j;
            fv2 val = v[rtop * 16 + j];
            ppb[(size_t)row * 4096 + col] = pack_bf2(val[0], val[1]);
        }
}

// Pass B2: gates 7..18, reads packed-bf16 psi. Fused transpose epilogue with
// [a][t] output layout + TIDX8 conflict-fixed LDS exchange.
__global__ __launch_bounds__(256) void pass_b2(const unsigned* __restrict__ psiB,
                                               unsigned short* __restrict__ Art,
                                               unsigned short* __restrict__ Ait,
                                               const c32* __restrict__ Gall) {
    __shared__ fv2 s[8192];
    const fv2* Gf = (const fv2*)Gall;
    int b = blockIdx.x >> 7;
    int chunk = blockIdx.x & 127;
    const unsigned* ppb = psiB + ((size_t)b << 20) + ((size_t)chunk << 13);
    int t = threadIdx.x;
    fv2 v[32], g[16], gs[16];
#pragma unroll
    for (int j = 0; j < 32; ++j) v[j] = unpack_bf2(ppb[(j << 8) | t]);
    load_gate2(Gf + 7 * GSTRIDE, g, gs);   gate_on32<3>(v, g, gs);
    load_gate2(Gf + 8 * GSTRIDE, g, gs);   gate_on32<2>(v, g, gs);
    load_gate2(Gf + 9 * GSTRIDE, g, gs);   gate_on32<1>(v, g, gs);
    load_gate2(Gf + 10 * GSTRIDE, g, gs);  gate_on32<0>(v, g, gs);
#pragma unroll
    for (int j = 0; j < 32; ++j) { int l = (j << 8) | t; s[SIDX(l)] = v[j]; }
    __syncthreads();
    int hi2 = (t >> 4) << 9, lo2 = t & 15;
#pragma unroll
    for (int j = 0; j < 32; ++j) { int l = hi2 | (j << 4) | lo2; v[j] = s[SIDX(l)]; }
    load_gate2(Gf + 11 * GSTRIDE, g, gs);  gate_on32<3>(v, g, gs);
    load_gate2(Gf + 12 * GSTRIDE, g, gs);  gate_on32<2>(v, g, gs);
    load_gate2(Gf + 13 * GSTRIDE, g, gs);  gate_on32<1>(v, g, gs);
    load_gate2(Gf + 14 * GSTRIDE, g, gs);  gate_on32<0>(v, g, gs);
    __syncthreads();
#pragma unroll
    for (int j = 0; j < 32; ++j) { int l = hi2 | (j << 4) | lo2; s[SIDX(l)] = v[j]; }
    __syncthreads();
#pragma unroll
    for (int j = 0; j < 32; ++j) { int l = (t << 5) | j; v[j] = s[SIDX(l)]; }
    load_gate2(Gf + 15 * GSTRIDE, g, gs);  gate_on32<3>(v, g, gs);
    load_gate2(Gf + 16 * GSTRIDE, g, gs);  gate_on32<2>(v, g, gs);
    load_gate2(Gf + 17 * GSTRIDE, g, gs);  gate_on32<1>(v, g, gs);
    load_gate2(Gf + 18 * GSTRIDE, g, gs);  gate_on32<0>(v, g, gs);
    // ---- transpose epilogue (TIDX8 swizzle + [a][t] output) ----
    __syncthreads();
    {
        int tlw = t >> 5;
        int abase = (t & 31) << 5;
#pragma unroll
        for (int j = 0; j < 32; ++j) {
            int a = abase + j;
            s[TIDX8(a, tlw)] = v[j];
        }
    }
    __syncthreads();
    {
        int w = t >> 6, lane = t & 63;
        size_t gb = (size_t)b << 20;
#pragma unroll
        for (int i = 0; i < 4; ++i) {
            int a = (w << 8) | (i << 6) | lane;
            unsigned short rr[8], ri[8];
#pragma unroll
            for (int tl = 0; tl < 8; ++tl) {
                fv2 q = s[TIDX8(a, tl)];
                rr[tl] = f2bf(q[0]);
                ri[tl] = f2bf(q[1]);
            }
            size_t dst = gb + ((size_t)a << 10) + (chunk << 3);   // [a][t] layout
            *reinterpret_cast<float4*>(Art + dst) = *reinterpret_cast<float4*>(rr);
            *reinterpret_cast<float4*>(Ait + dst) = *reinterpret_cast<float4*>(ri);
        }
    }
}

// gram_mfma5c: best variant (128x128 tiles, gll-staged 128KB dbuf LDS,
// 1 barrier/K-step + setprio, coalesced LDS mirror epilogue).
__global__ __launch_bounds__(512) void gram_mfma5c(const unsigned short* __restrict__ Art,
                                                   const unsigned short* __restrict__ Ait,
                                                   float2* __restrict__ out) {
    __shared__ __align__(16) unsigned short lds[2][4][8192];   // 128 KB
    int hw = blockIdx.x;
    int virt = (hw & 7) * 18 + (hw >> 3);        // bijective: 144 = 8*18, XCD-chunked
    int b = virt / 36;
    int rem = virt - b * 36;                     // triangular decode over 8x8, ia <= ic
    int ia = 0;
    while (rem >= 8 - ia) { rem -= 8 - ia; ++ia; }
    int ic = ia + rem;
    int a0 = ia * 128, c0 = ic * 128;
    int tid = threadIdx.x;
    int lane = tid & 63, w = tid >> 6;           // 8 waves
    int wm = w & 3, wn = w >> 2;                 // wave-tile: rows wm*32, cols wn*64
    int arr = w >> 1, half = w & 1;
    const unsigned short* sp = (arr & 1) ? Ait : Art;
    int prow = (arr < 2) ? a0 : c0;
    int srow = lane >> 3, sslot = lane & 7;
    size_t gb = (size_t)b << 20;

    f32x4 accRe[2][4], accIm[2][4];
#pragma unroll
    for (int m = 0; m < 2; m++)
#pragma unroll
        for (int n = 0; n < 4; n++) { accRe[m][n] = (f32x4)0.f; accIm[m][n] = (f32x4)0.f; }

#define STAGE5(KT, BUF)                                                                   \
    {                                                                                     \
        _Pragma("unroll")                                                                 \
        for (int i = 0; i < 8; ++i) {                                                     \
            int r = (half << 6) | (i << 3) | srow;                                        \
            int sl = sslot ^ srow;                                                        \
            const unsigned short* gp = sp + gb + ((size_t)(prow + r) << 10) + (KT) * 64 + sl * 8; \
            gll16(gp, &lds[BUF][arr][((half << 6) | (i << 3)) * 64 + lane * 8]);          \
        }                                                                                 \
    }

    STAGE5(0, 0);
    for (int kt = 0; kt < 16; ++kt) {
        int cur = kt & 1;
        asm volatile("s_waitcnt vmcnt(0)" ::: "memory");
        __builtin_amdgcn_s_barrier();
        __builtin_amdgcn_sched_barrier(0);
        if (kt < 15) STAGE5(kt + 1, cur ^ 1);
        __builtin_amdgcn_s_setprio(1);
#pragma unroll
        for (int kk = 0; kk < 2; ++kk) {
            int sbase = kk * 4 + (lane >> 4);    // 16B-slot index 0..7
            short8 am[2][2], bn[4][2];
#pragma unroll
            for (int m = 0; m < 2; m++) {
                int r = wm * 32 + m * 16 + (lane & 15);
                int off = r * 64 + ((sbase ^ (r & 7)) << 3);
                am[m][0] = *reinterpret_cast<const short8*>(&lds[cur][0][off]);
                am[m][1] = *reinterpret_cast<const short8*>(&lds[cur][1][off]);
            }
#pragma unroll
            for (int n = 0; n < 4; n++) {
                int r = wn * 64 + n * 16 + (lane & 15);
                int off = r * 64 + ((sbase ^ (r & 7)) << 3);
                bn[n][0] = *reinterpret_cast<const short8*>(&lds[cur][2][off]);
                bn[n][1] = *reinterpret_cast<const short8*>(&lds[cur][3][off]);
            }
#pragma unroll
            for (int m = 0; m < 2; m++) {
                u32x4 tn = *reinterpret_cast<u32x4*>(&am[m][0]) ^ 0x80008000u;
                short8 arn = *reinterpret_cast<short8*>(&tn);
#pragma unroll
                for (int n = 0; n < 4; n++) {
                    accRe[m][n] = __builtin_amdgcn_mfma_f32_16x16x32_bf16(am[m][0], bn[n][0], accRe[m][n], 0, 0, 0);
                    accRe[m][n] = __builtin_amdgcn_mfma_f32_16x16x32_bf16(am[m][1], bn[n][1], accRe[m][n], 0, 0, 0);
                    accIm[m][n] = __builtin_amdgcn_mfma_f32_16x16x32_bf16(am[m][1], bn[n][0], accIm[m][n], 0, 0, 0);
                    accIm[m][n] = __builtin_amdgcn_mfma_f32_16x16x32_bf16(arn,      bn[n][1], accIm[m][n], 0, 0, 0);
                }
            }
        }
        __builtin_amdgcn_s_setprio(0);
        asm volatile("s_waitcnt lgkmcnt(0)" ::: "memory");
        __builtin_amdgcn_sched_barrier(0);
    }
#undef STAGE5
    // ---- epilogue ----
    size_t ob = gb;
#pragma unroll
    for (int m = 0; m < 2; m++)
#pragma unroll
        for (int n = 0; n < 4; n++)
#pragma unroll
            for (int r = 0; r < 4; r++) {
                int a = a0 + wm * 32 + m * 16 + (lane >> 4) * 4 + r;
                int c = c0 + wn * 64 + n * 16 + (lane & 15);
                out[ob + ((size_t)a << 10) + c] = make_float2(accRe[m][n][r], accIm[m][n][r]);
            }
    if (ia != ic) {
        float2* mlds = reinterpret_cast<float2*>(&lds[0][0][0]);
#pragma unroll
        for (int h = 0; h < 2; ++h) {
            __syncthreads();
            if (wn == h) {
#pragma unroll
                for (int m = 0; m < 2; m++)
#pragma unroll
                    for (int n = 0; n < 4; n++)
#pragma unroll
                        for (int r = 0; r < 4; r++) {
                            int a_l = wm * 32 + m * 16 + (lane >> 4) * 4 + r;   // 0..127
                            int c_l = n * 16 + (lane & 15);                     // 0..63 within half
                            mlds[c_l * 131 + a_l] = make_float2(accRe[m][n][r], -accIm[m][n][r]);
                        }
            }
            __syncthreads();
#pragma unroll
            for (int i = 0; i < 16; ++i) {
                int p = tid + (i << 9);          // 8192 float2 = [64 c-rows][128 a-cols]
                int row = p >> 7, col = p & 127;
                out[ob + ((size_t)(c0 + h * 64 + row) << 10) + a0 + col] = mlds[row * 131 + col];
            }
        }
    }
}

extern "C" void kernel_launch(void* const* d_in, const int* in_sizes, int n_in,
                              void* d_out, int out_size, void* d_ws, size_t ws_size,
                              hipStream_t stream) {
    const float* x = (const float*)d_in[0];
    const float* weight = (const float*)d_in[1];
    const size_t psiBytes = (size_t)BATCH * DIM * sizeof(unsigned);  // 16 MB (packed bf16)
    unsigned* psiB = (unsigned*)d_ws;
    c32* G = (c32*)((char*)d_ws + psiBytes);                         // 19*32 c32
    unsigned short* Art = (unsigned short*)((char*)d_ws + psiBytes + 65536);
    unsigned short* Ait = Art + (size_t)BATCH * DIM;                 // 8 MB each

    build_gates<<<1, 64, 0, stream>>>(weight, G);
    pass_a2<<<BATCH * 128, 256, 0, stream>>>(x, psiB, G);            // gates 0..6 -> packed bf16 psi
    pass_b2<<<BATCH * 128, 256, 0, stream>>>(psiB, Art, Ait, G);     // gates 7..18 -> bf16 [a][t]
    gram_mfma5c<<<144, 512, 0, stream>>>(Art, Ait, (float2*)d_out);
}